// Round 16
// baseline (181.362 us; speedup 1.0000x reference)
//
#include <hip/hip_runtime.h>
#include <hip/hip_bf16.h>

#define BB 2
#define NN 4096
#define CC 32
#define PG 16   // 16 k-groups of 8 -> K=128

typedef __attribute__((ext_vector_type(8))) short short8;
typedef __attribute__((ext_vector_type(4))) float f32x4;
typedef __attribute__((ext_vector_type(16))) float f32x16;

__device__ __forceinline__ unsigned short f2bf(float v) {
    return __builtin_bit_cast(unsigned short, __float2bfloat16(v));
}

// Panel layout for 32x32x16 bf16 MFMA: per (b, n32, kb16) a 1024B chunk.
// Lane l loads short8 at l*16B: r = l&31, k8 = l>>5, elements k = k8*8+e.
// Chunk short offset = ((k8*32 + r)*8 + e).
__device__ __forceinline__ size_t chunk_off(int b, int n32, int kb) {
    return (((size_t)b * 128 + n32) * 8 + kb) * 512;
}

// ---------------- prep: thread per (g, b, n); one 16B store per panel -------
// k = g*8 + e  ->  kb = g>>1, k8 = g&1
__global__ __launch_bounds__(256) void prep_kernel(
    const float* __restrict__ pc1, const float* __restrict__ pc2,
    const float* __restrict__ xfeat, const float* __restrict__ yfeat,
    const float* __restrict__ quat,
    __hip_bfloat16* __restrict__ Xp, __hip_bfloat16* __restrict__ Yp,
    float* __restrict__ px, float* __restrict__ py)
{
    int idx = blockIdx.x * 256 + threadIdx.x;   // PG*BB*NN = 131072
    if (idx >= PG * BB * NN) return;
    int g = idx >> 13;            // k-group, slowest -> n stays coalesced
    int rem = idx & 8191;
    int b = rem >> 12;
    int n = rem & 4095;
    int k0 = g * 8;

    float qx = quat[b*4+0], qy = quat[b*4+1], qz = quat[b*4+2], qw = quat[b*4+3];
    float qi = rsqrtf(qx*qx + qy*qy + qz*qz + qw*qw);
    qx *= qi; qy *= qi; qz *= qi; qw *= qi;
    float r00 = 1.f-2.f*(qy*qy+qz*qz), r01 = 2.f*(qx*qy-qz*qw), r02 = 2.f*(qx*qz+qy*qw);
    float r10 = 2.f*(qx*qy+qz*qw), r11 = 1.f-2.f*(qx*qx+qz*qz), r12 = 2.f*(qy*qz-qx*qw);
    float r20 = 2.f*(qx*qz-qy*qw), r21 = 2.f*(qy*qz+qx*qw), r22 = 1.f-2.f*(qx*qx+qy*qy);

    unsigned short hx[8], hy[8];
    float sx = 0.f, sy = 0.f;
    #pragma unroll
    for (int t = 0; t < 8; ++t) {       // t static -> no runtime-indexed arrays
        int k = k0 + t;
        float vx = 0.f, wy = 0.f;
        if (k < 99) {
            int c = k / 3, comp = k - 3*c;
            const float* xsrc = (c == 0)
                ? (pc1 + (size_t)(b*3 + comp) * NN)
                : (xfeat + ((size_t)(b*CC + c-1)*3 + comp) * NN);
            vx = xsrc[n];
            const float* ybase = (c == 0)
                ? (pc2 + (size_t)b*3*NN)
                : (yfeat + (size_t)(b*CC + c-1)*3*NN);
            float u0 = ybase[n], u1 = ybase[NN + n], u2 = ybase[2*NN + n];
            wy = (comp == 0) ? r00*u0 + r01*u1 + r02*u2
               : (comp == 1) ? r10*u0 + r11*u1 + r12*u2
                             : r20*u0 + r21*u1 + r22*u2;
        }
        sx += vx*vx; sy += wy*wy;
        hx[t] = f2bf(vx);
        hy[t] = f2bf(wy);
    }

    size_t off = chunk_off(b, n >> 5, g >> 1) + (size_t)(((g & 1)*32 + (n & 31)) * 8);
    short8 vx8, vy8;
    #pragma unroll
    for (int t = 0; t < 8; ++t) { vx8[t] = (short)hx[t]; vy8[t] = (short)hy[t]; }
    *(short8*)(Xp + off) = vx8;         // one 16B aligned store
    *(short8*)(Yp + off) = vy8;         // one 16B aligned store

    int pidx = g * (BB*NN) + b*NN + n;
    px[pidx] = sx; py[pidx] = sy;
}

// ---------------- reduce: sum 16 partials per point; zero out[0] ------------
__global__ __launch_bounds__(256) void reduce_kernel(
    const float* __restrict__ px, const float* __restrict__ py,
    float* __restrict__ xn, float* __restrict__ yn, float* __restrict__ out)
{
    int i = blockIdx.x * 256 + threadIdx.x;
    if (i >= BB * NN) return;
    float sx = 0.f, sy = 0.f;
    #pragma unroll
    for (int g = 0; g < PG; ++g) { sx += px[g*(BB*NN) + i]; sy += py[g*(BB*NN) + i]; }
    xn[i] = sx; yn[i] = sy;
    if (i == 0) out[0] = 0.f;
}

// ------- gram: 128x128/block, 32x32x16 MFMA, row-contiguous scalar stores ---
__global__ __launch_bounds__(256) void gram_kernel(
    const __hip_bfloat16* __restrict__ Xp, const __hip_bfloat16* __restrict__ Yp,
    const float* __restrict__ xn, const float* __restrict__ yn,
    float* __restrict__ out)
{
    __shared__ float red[4];
    // XCD-chunked swizzle (2048 = 8 XCD * 256)
    int bid = blockIdx.x;
    int work = (bid & 7) * 256 + (bid >> 3);
    int b  = work >> 10;
    int rem = work & 1023;
    int tN = rem >> 5;            // row tile (X)
    int tM = rem & 31;            // col tile (Y)

    int tid = threadIdx.x;
    int wid = tid >> 6, lane = tid & 63;
    int wr = wid >> 1, wc = wid & 1;
    int cl = lane & 31, hl = lane >> 5;

    // acc[fi][fj] = X_frag(fi) . Y_frag(fj)^T :
    // gram col = lane&31 (B=Y, contiguous in memory!), gram row = (r&3)+8*(r>>2)+4*hl
    f32x16 acc[2][2] = {};
    #pragma unroll
    for (int kb = 0; kb < 8; ++kb) {
        short8 xfr[2], yfr[2];
        #pragma unroll
        for (int fi = 0; fi < 2; ++fi)
            xfr[fi] = ((const short8*)(Xp + chunk_off(b, tN*4 + wr*2 + fi, kb)))[lane];
        #pragma unroll
        for (int fj = 0; fj < 2; ++fj)
            yfr[fj] = ((const short8*)(Yp + chunk_off(b, tM*4 + wc*2 + fj, kb)))[lane];
        #pragma unroll
        for (int fi = 0; fi < 2; ++fi)
            #pragma unroll
            for (int fj = 0; fj < 2; ++fj)
                acc[fi][fj] = __builtin_amdgcn_mfma_f32_32x32x16_bf16(
                    xfr[fi], yfr[fj], acc[fi][fj], 0, 0, 0);
    }

    float lsum = 0.f;
    #pragma unroll
    for (int fi = 0; fi < 2; ++fi) {
        int rbase = tN*128 + wr*64 + fi*32 + 4*hl;
        f32x4 xq0 = *(const f32x4*)(xn + b*NN + rbase);
        f32x4 xq1 = *(const f32x4*)(xn + b*NN + rbase + 8);
        f32x4 xq2 = *(const f32x4*)(xn + b*NN + rbase + 16);
        f32x4 xq3 = *(const f32x4*)(xn + b*NN + rbase + 24);
        #pragma unroll
        for (int fj = 0; fj < 2; ++fj) {
            int col = tM*128 + wc*64 + fj*32 + cl;
            float yv = yn[b*NN + col];
            #pragma unroll
            for (int r = 0; r < 16; ++r) {
                int grp = r >> 2, rr = (r & 3) + 8*grp;
                float xv = (grp == 0) ? xq0[r & 3]
                         : (grp == 1) ? xq1[r & 3]
                         : (grp == 2) ? xq2[r & 3]
                                      : xq3[r & 3];
                float sq = fmaxf(xv + yv - 2.f * acc[fi][fj][r], 0.f);
                float e = __expf(-sq * 0.005f);
                float g = (e > 0.1f) ? e : 0.f;
                // lanes 0-31 / 32-63: two contiguous 128B runs per instruction
                out[1 + (size_t)(b*NN + rbase + rr) * NN + col] = g;
                lsum += g;
            }
        }
    }

    #pragma unroll
    for (int off = 32; off > 0; off >>= 1) lsum += __shfl_down(lsum, off, 64);
    if (lane == 0) red[wid] = lsum;
    __syncthreads();
    if (tid == 0) atomicAdd(out, red[0] + red[1] + red[2] + red[3]);
}

extern "C" void kernel_launch(void* const* d_in, const int* in_sizes, int n_in,
                              void* d_out, int out_size, void* d_ws, size_t ws_size,
                              hipStream_t stream) {
    const float* pc1   = (const float*)d_in[0];
    const float* pc2   = (const float*)d_in[1];
    const float* xfeat = (const float*)d_in[2];
    const float* yfeat = (const float*)d_in[3];
    const float* quat  = (const float*)d_in[4];
    float* out = (float*)d_out;

    __hip_bfloat16* Xp = (__hip_bfloat16*)d_ws;                     // 2 MB
    __hip_bfloat16* Yp = Xp + (size_t)BB * 128 * 8 * 512;           // 2 MB
    float* xn = (float*)(Yp + (size_t)BB * 128 * 8 * 512);          // 32 KB
    float* yn = xn + (size_t)BB * NN;                               // 32 KB
    float* px = yn + (size_t)BB * NN;                               // 512 KB
    float* py = px + (size_t)PG * BB * NN;                          // 512 KB

    prep_kernel<<<(PG*BB*NN + 255)/256, 256, 0, stream>>>(
        pc1, pc2, xfeat, yfeat, quat, Xp, Yp, px, py);
    reduce_kernel<<<(BB*NN + 255)/256, 256, 0, stream>>>(px, py, xn, yn, out);
    gram_kernel<<<2048, 256, 0, stream>>>(Xp, Yp, xn, yn, out);
}